// Round 5
// baseline (497.063 us; speedup 1.0000x reference)
//
#include <hip/hip_runtime.h>
#include <cstdint>
#include <cstddef>

// S=4096, D=1024, H=16, DH=64, F=4096. fp32 in/out, bf16 MFMA compute.

typedef __attribute__((ext_vector_type(8))) __bf16 bf16x8;
typedef __attribute__((ext_vector_type(4))) float f32x4;
typedef __attribute__((ext_vector_type(16))) float f32x16;
typedef __attribute__((ext_vector_type(4))) unsigned int u32x4;

__device__ inline unsigned short f2bf(float f) {
  unsigned int u = __float_as_uint(f);
  u += 0x7fffu + ((u >> 16) & 1u);   // round-to-nearest-even
  return (unsigned short)(u >> 16);
}

__device__ inline void gload_lds16(const unsigned short* g, unsigned short* l) {
  __builtin_amdgcn_global_load_lds(
      (const __attribute__((address_space(1))) void*)g,
      (__attribute__((address_space(3))) void*)l, 16, 0, 0);
}

// ---------------- transpose + fp32->bf16 : in[K][N] -> out[N][K] ----------------
__global__ __launch_bounds__(256) void transpose_cvt(const float* __restrict__ in,
                                                     unsigned short* __restrict__ out,
                                                     int K, int N) {
  __shared__ float t[32][33];
  int nb = blockIdx.x * 32, kb = blockIdx.y * 32;
  int tx = threadIdx.x & 31, ty = threadIdx.x >> 5;  // 32 x 8
#pragma unroll
  for (int i = 0; i < 32; i += 8)
    t[ty + i][tx] = in[(size_t)(kb + ty + i) * N + nb + tx];
  __syncthreads();
#pragma unroll
  for (int i = 0; i < 32; i += 8)
    out[(size_t)(nb + ty + i) * K + kb + tx] = f2bf(t[tx][ty + i]);
}

// ---------------- concat 3 bias vectors of 1024 ----------------
__global__ __launch_bounds__(256) void concat3(const float* __restrict__ a,
                                               const float* __restrict__ b,
                                               const float* __restrict__ c,
                                               float* __restrict__ out) {
  int i = blockIdx.x * 256 + threadIdx.x;  // 0..3071
  float v = (i < 1024) ? a[i] : (i < 2048 ? b[i - 1024] : c[i - 2048]);
  out[i] = v;
}

// ---------------- LayerNorm row (D=1024), output bf16 ----------------
__global__ __launch_bounds__(256) void ln_kernel(const float* __restrict__ x,
                                                 const float* __restrict__ gamma,
                                                 const float* __restrict__ beta,
                                                 unsigned short* __restrict__ y) {
  int row = blockIdx.x, tid = threadIdx.x;
  const float4 v = ((const float4*)(x + (size_t)row * 1024))[tid];
  float s = v.x + v.y + v.z + v.w;
#pragma unroll
  for (int off = 1; off < 64; off <<= 1) s += __shfl_xor(s, off);
  __shared__ float red1[4], red2[4];
  int wave = tid >> 6;
  if ((tid & 63) == 0) red1[wave] = s;
  __syncthreads();
  float mu = (red1[0] + red1[1] + red1[2] + red1[3]) * (1.0f / 1024.0f);
  float dx = v.x - mu, dy = v.y - mu, dz = v.z - mu, dw = v.w - mu;
  float s2 = dx * dx + dy * dy + dz * dz + dw * dw;
#pragma unroll
  for (int off = 1; off < 64; off <<= 1) s2 += __shfl_xor(s2, off);
  if ((tid & 63) == 0) red2[wave] = s2;
  __syncthreads();
  float var = (red2[0] + red2[1] + red2[2] + red2[3]) * (1.0f / 1024.0f);
  float inv = rsqrtf(var + 1e-6f);
  int c = tid * 4;
  ushort4 o;
  o.x = f2bf(dx * inv * gamma[c + 0] + beta[c + 0]);
  o.y = f2bf(dy * inv * gamma[c + 1] + beta[c + 1]);
  o.z = f2bf(dz * inv * gamma[c + 2] + beta[c + 2]);
  o.w = f2bf(dw * inv * gamma[c + 3] + beta[c + 3]);
  ((ushort4*)(y + (size_t)row * 1024))[tid] = o;
}

// ---------------- GEMM: C[M][N] = A[M][K](bf16) * BT[N][K](bf16) + bias ----------------
// m97 structure: TMx128 tile, BK=32, global_load_lds staging, pitch-32 LDS.
template <int TM, bool GELU, bool RES, bool OUTBF, bool SCALEQ>
__global__ __launch_bounds__(256) void gemm_bt(const unsigned short* __restrict__ A,
                                               const unsigned short* __restrict__ BT,
                                               const float* __restrict__ bias,
                                               const float* __restrict__ res,
                                               void* __restrict__ out,
                                               int M, int N, int K) {
  constexpr int AI = TM / 32;                 // acc i-tiles per wave (4 or 2)
  __shared__ unsigned short As[TM * 32];
  __shared__ unsigned short Bs[128 * 32];
  int bm = blockIdx.x, bn = blockIdx.y;
  int tid = threadIdx.x;
  int wave = tid >> 6, lane = tid & 63, quad = lane >> 4, l16 = lane & 15;
  int wrow = (wave >> 1) * (16 * AI), wcol = (wave & 1) * 64;
  f32x4 zero = {0.f, 0.f, 0.f, 0.f};
  f32x4 acc[AI][4];
#pragma unroll
  for (int i = 0; i < AI; i++)
#pragma unroll
    for (int j = 0; j < 4; j++) acc[i][j] = zero;

  const int srow = tid >> 2;            // 0..63
  const int scol = (tid & 3) * 8;       // shorts
  const unsigned short* aG0 = A + (size_t)(bm * TM + srow) * K + scol;
  const unsigned short* aG1 = A + (size_t)(bm * TM + 64 + srow) * K + scol;
  const unsigned short* bG0 = BT + (size_t)(bn * 128 + srow) * K + scol;
  const unsigned short* bG1 = BT + (size_t)(bn * 128 + 64 + srow) * K + scol;
  unsigned short* aL0 = As + (size_t)tid * 8;
  unsigned short* aL1 = As + (size_t)(256 + tid) * 8;
  unsigned short* bL0 = Bs + (size_t)tid * 8;
  unsigned short* bL1 = Bs + (size_t)(256 + tid) * 8;

  for (int k0 = 0; k0 < K; k0 += 32) {
    __syncthreads();
    gload_lds16(aG0 + k0, aL0);
    if (TM == 128) gload_lds16(aG1 + k0, aL1);
    gload_lds16(bG0 + k0, bL0);
    gload_lds16(bG1 + k0, bL1);
    __syncthreads();
    bf16x8 af[AI], bfr[4];
#pragma unroll
    for (int i = 0; i < AI; i++) af[i] = *(const bf16x8*)&As[(wrow + i * 16 + l16) * 32 + quad * 8];
#pragma unroll
    for (int j = 0; j < 4; j++) bfr[j] = *(const bf16x8*)&Bs[(wcol + j * 16 + l16) * 32 + quad * 8];
#pragma unroll
    for (int i = 0; i < AI; i++)
#pragma unroll
      for (int j = 0; j < 4; j++)
        acc[i][j] = __builtin_amdgcn_mfma_f32_16x16x32_bf16(af[i], bfr[j], acc[i][j], 0, 0, 0);
  }

#pragma unroll
  for (int i = 0; i < AI; i++) {
    int row = bm * TM + wrow + i * 16 + quad * 4;
#pragma unroll
    for (int j = 0; j < 4; j++) {
      int col = bn * 128 + wcol + j * 16 + l16;
      float bv = bias[col];
      // 0.125/sqrt(DH) * log2(e): softmax uses exp2
      float qs = (SCALEQ && col < 1024) ? 0.18033688f : 1.0f;
#pragma unroll
      for (int r = 0; r < 4; r++) {
        float v = (acc[i][j][r] + bv) * qs;
        if (GELU) v = 0.5f * v * (1.0f + erff(v * 0.70710678118654752440f));
        if (RES) v += res[(size_t)(row + r) * N + col];
        if (OUTBF)
          ((unsigned short*)out)[(size_t)(row + r) * N + col] = f2bf(v);
        else
          ((float*)out)[(size_t)(row + r) * N + col] = v;
      }
    }
  }
}

// ---------------- prep K/V tiles for attention ----------------
// K: Kp[h][t][row(kv)][chunk-swizzled d]  (8KB tiles; chunk c at position c^(row&7))
// V: Vp[h][t] = exact transposed+swizzled 64x64 LDS image ([d][kv-dwords swizzled])
__global__ __launch_bounds__(256) void prep_kv(const unsigned short* __restrict__ qkv,
                                               unsigned short* __restrict__ Kp,
                                               unsigned short* __restrict__ Vp) {
  __shared__ unsigned short Vt[64 * 64];
  int t = blockIdx.x, h = blockIdx.y;
  int tid = threadIdx.x;
  const int r2 = tid >> 3, c0 = (tid & 7) * 8;
  size_t tb = ((size_t)h * 64 + t) * 4096;
  {
    const unsigned short* kp = qkv + (size_t)(t * 64 + r2) * 3072 + 1024 + h * 64 + c0;
    uint4 k0 = *(const uint4*)kp;
    uint4 k1 = *(const uint4*)(kp + (size_t)32 * 3072);
    int c = c0 >> 3;
    *(uint4*)(Kp + tb + r2 * 64 + ((c ^ (r2 & 7)) << 3)) = k0;
    int rb = r2 + 32;
    *(uint4*)(Kp + tb + rb * 64 + ((c ^ (rb & 7)) << 3)) = k1;
  }
  {
    const unsigned short* vp = qkv + (size_t)(t * 64 + 2 * r2) * 3072 + 2048 + h * 64 + c0;
    uint4 v0 = *(const uint4*)vp;
    uint4 v1 = *(const uint4*)(vp + 3072);
    const unsigned short* p0 = (const unsigned short*)&v0;
    const unsigned short* p1 = (const unsigned short*)&v1;
#pragma unroll
    for (int dd = 0; dd < 8; dd++) {
      int d = c0 + dd;
      int swz = ((d >> 3) ^ d) & 7;
      int dcol = (((r2 >> 2) ^ swz) << 2) | (r2 & 3);   // dword units within row
      unsigned int pk = (unsigned int)p0[dd] | ((unsigned int)p1[dd] << 16);
      *(unsigned int*)&Vt[d * 64 + dcol * 2] = pk;
    }
  }
  __syncthreads();
  *(uint4*)(Vp + tb + tid * 8) = *(const uint4*)&Vt[tid * 8];
  *(uint4*)(Vp + tb + 2048 + tid * 8) = *(const uint4*)&Vt[2048 + tid * 8];
}

// ---------------- Flash attention: prepped K/V tiles -> ctx[S][1024] bf16 ----------------
// grid = (S/64, H), block 256 (4 waves): wave = (qsub, kvh). Q in registers.
// Single-barrier double-buffered K-loop: stage(t+1) issued right after barrier(t).
// S^T = K Q^T keeps P in registers; no-max base-2 softmax (log2e folded into Q scale).
__global__ __launch_bounds__(256) void attn_kernel(const unsigned short* __restrict__ qkv,
                                                   const unsigned short* __restrict__ Kp,
                                                   const unsigned short* __restrict__ Vp,
                                                   unsigned short* __restrict__ ctx) {
  __shared__ unsigned short smem[16384 + 256];  // 2 x (Ks 4096 + Vt 4096) shorts; union comb/lpart
  float* comb = (float*)smem;                   // [2][32][64] fp32 (16 KB)
  float* lpart = (float*)(smem + 16384);        // [2][2][32]
  int qt = blockIdx.x, h = blockIdx.y;
  int tid = threadIdx.x;
  int w = tid >> 6, lane = tid & 63;
  int l31 = lane & 31, hi = lane >> 5;
  int qsub = w & 1, kvh = w >> 1;

  // Q fragments (B-operand: n=q=l31, k=d). Pre-scaled by 0.125*log2e in QKV epilogue.
  bf16x8 qf[4];
  {
    const unsigned short* qp = qkv + (size_t)(qt * 64 + qsub * 32 + l31) * 3072 + h * 64 + hi * 8;
#pragma unroll
    for (int kk = 0; kk < 4; kk++) qf[kk] = *(const bf16x8*)(qp + kk * 16);
  }

  const size_t hb = (size_t)h * 64 * 4096;
  f32x16 accO0, accO1;
  float lp = 0.f;
#pragma unroll
  for (int r = 0; r < 16; r++) { accO0[r] = 0.f; accO1[r] = 0.f; }

  // prologue: stage tile 0 into buffer 0
  {
    unsigned short* Kd = smem;
    unsigned short* Vd = smem + 4096;
    gload_lds16(Kp + hb + tid * 8, Kd + tid * 8);
    gload_lds16(Kp + hb + 2048 + tid * 8, Kd + 2048 + tid * 8);
    gload_lds16(Vp + hb + tid * 8, Vd + tid * 8);
    gload_lds16(Vp + hb + 2048 + tid * 8, Vd + 2048 + tid * 8);
  }

  // loop-invariant LDS read offsets
  const int krow = kvh * 32 + l31;
  int koff[4];
#pragma unroll
  for (int kk = 0; kk < 4; kk++)
    koff[kk] = krow * 64 + (((kk * 2 + hi) ^ (krow & 7)) << 3);
  const int dA = l31, dB = 32 + l31;
  const int swA = ((dA >> 3) ^ dA) & 7, swB = ((dB >> 3) ^ dB) & 7;

  for (int kv0 = 0; kv0 < 4096; kv0 += 64) {
    int cur = (kv0 >> 6) & 1;
    const unsigned short* Ks = smem + cur * 8192;
    const unsigned short* Vt = Ks + 4096;
    __syncthreads();   // stage(cur) landed; prior reads of other buffer done
    if (kv0 + 64 < 4096) {
      size_t tb = hb + (size_t)((kv0 >> 6) + 1) * 4096;
      unsigned short* Kd = smem + (cur ^ 1) * 8192;
      unsigned short* Vd = Kd + 4096;
      gload_lds16(Kp + tb + tid * 8, Kd + tid * 8);
      gload_lds16(Kp + tb + 2048 + tid * 8, Kd + 2048 + tid * 8);
      gload_lds16(Vp + tb + tid * 8, Vd + tid * 8);
      gload_lds16(Vp + tb + 2048 + tid * 8, Vd + 2048 + tid * 8);
    }

    // S^T tile [32 kv][32 q]: A = K (m=kv), B = Q^T (n=q)
    f32x16 accS;
#pragma unroll
    for (int r = 0; r < 16; r++) accS[r] = 0.f;
#pragma unroll
    for (int kk = 0; kk < 4; kk++) {
      bf16x8 kf = *(const bf16x8*)&Ks[koff[kk]];
      accS = __builtin_amdgcn_mfma_f32_32x32x16_bf16(kf, qf[kk], accS, 0, 0, 0);
    }
    // P = 2^S; per-lane row-sum; pack pairs via v_perm
    unsigned int pd[8];
#pragma unroll
    for (int i = 0; i < 8; i++) {
      float a = exp2f(accS[2 * i]);
      float b = exp2f(accS[2 * i + 1]);
      lp += a + b;
      pd[i] = __builtin_amdgcn_perm(__float_as_uint(b) + 0x8000u,
                                    __float_as_uint(a) + 0x8000u, 0x07060302);
    }
    unsigned int qd[8];
#pragma unroll
    for (int i = 0; i < 8; i++) qd[i] = (unsigned int)__shfl_xor((int)pd[i], 32);
    u32x4 f0 = { hi ? qd[2] : pd[0], hi ? qd[3] : pd[1], hi ? pd[2] : qd[0], hi ? pd[3] : qd[1] };
    u32x4 f1 = { hi ? qd[6] : pd[4], hi ? qd[7] : pd[5], hi ? pd[6] : qd[4], hi ? pd[7] : qd[5] };
    bf16x8 pa0 = __builtin_bit_cast(bf16x8, f0);
    bf16x8 pa1 = __builtin_bit_cast(bf16x8, f1);
    // O += P V
#pragma unroll
    for (int kk = 0; kk < 2; kk++) {
      bf16x8 pa = kk ? pa1 : pa0;
      int c = kvh * 4 + kk * 2 + hi;
      bf16x8 vfA = *(const bf16x8*)&Vt[dA * 64 + ((c ^ swA) << 3)];
      bf16x8 vfB = *(const bf16x8*)&Vt[dB * 64 + ((c ^ swB) << 3)];
      accO0 = __builtin_amdgcn_mfma_f32_32x32x16_bf16(pa, vfA, accO0, 0, 0, 0);
      accO1 = __builtin_amdgcn_mfma_f32_32x32x16_bf16(pa, vfB, accO1, 0, 0, 0);
    }
  }

  __syncthreads();   // all waves done reading Ks/Vt before aliasing as comb/lpart
  lp += __shfl_xor(lp, 32);
  if (hi == 0) lpart[(kvh * 2 + qsub) * 32 + l31] = lp;
  if (kvh == 1) {
#pragma unroll
    for (int r = 0; r < 16; r++) {
      int q = (r & 3) + 8 * (r >> 2) + 4 * hi;
      comb[(qsub * 32 + q) * 64 + l31] = accO0[r];
      comb[(qsub * 32 + q) * 64 + 32 + l31] = accO1[r];
    }
  }
  __syncthreads();
  if (kvh == 0) {
#pragma unroll
    for (int r = 0; r < 16; r++) {
      int q = (r & 3) + 8 * (r >> 2) + 4 * hi;
      float l = lpart[qsub * 32 + q] + lpart[(2 + qsub) * 32 + q];
      float inv = 1.0f / l;
      float v0 = (accO0[r] + comb[(qsub * 32 + q) * 64 + l31]) * inv;
      float v1 = (accO1[r] + comb[(qsub * 32 + q) * 64 + 32 + l31]) * inv;
      int row = qt * 64 + qsub * 32 + q;
      size_t o = (size_t)row * 1024 + h * 64;
      ctx[o + l31] = f2bf(v0);
      ctx[o + 32 + l31] = f2bf(v1);
    }
  }
}

// ---------------- launcher ----------------
extern "C" void kernel_launch(void* const* d_in, const int* in_sizes, int n_in,
                              void* d_out, int out_size, void* d_ws, size_t ws_size,
                              hipStream_t stream) {
  const float* x   = (const float*)d_in[0];
  const float* Wq  = (const float*)d_in[1];
  const float* bq  = (const float*)d_in[2];
  const float* Wk  = (const float*)d_in[3];
  const float* bk  = (const float*)d_in[4];
  const float* Wv  = (const float*)d_in[5];
  const float* bv  = (const float*)d_in[6];
  const float* Wo  = (const float*)d_in[7];
  const float* bo  = (const float*)d_in[8];
  const float* g1  = (const float*)d_in[9];
  const float* be1 = (const float*)d_in[10];
  const float* g2  = (const float*)d_in[11];
  const float* be2 = (const float*)d_in[12];
  const float* W1  = (const float*)d_in[13];
  const float* b1  = (const float*)d_in[14];
  const float* W2  = (const float*)d_in[15];
  const float* b2  = (const float*)d_in[16];
  float* out = (float*)d_out;

  char* p = (char*)d_ws;
  unsigned short* WqkvT = (unsigned short*)p; p += (size_t)3072 * 1024 * 2;  // [3072][1024]
  unsigned short* WoT   = (unsigned short*)p; p += (size_t)1024 * 1024 * 2;  // [1024][1024]
  unsigned short* W1T   = (unsigned short*)p; p += (size_t)4096 * 1024 * 2;  // [4096][1024]
  unsigned short* W2T   = (unsigned short*)p; p += (size_t)1024 * 4096 * 2;  // [1024][4096]
  float*          bqkv  = (float*)p;          p += 16384;                    // [3072]
  unsigned short* y1    = (unsigned short*)p; p += (size_t)4096 * 1024 * 2;  // LN out
  unsigned short* qkvb  = (unsigned short*)p; p += (size_t)4096 * 3072 * 2;  // [S][3072]
  unsigned short* ctxb  = (unsigned short*)p; p += (size_t)4096 * 1024 * 2;  // [S][1024]
  float*          x1    = (float*)p;          p += (size_t)4096 * 1024 * 4;  // residual fp32
  unsigned short* Kp    = (unsigned short*)p; p += (size_t)16 * 64 * 4096 * 2;  // prepped K tiles
  unsigned short* Vp    = (unsigned short*)p; p += (size_t)16 * 64 * 4096 * 2;  // prepped V tiles
  unsigned short* hbuf  = qkvb;  // [S][4096] bf16 aliases qkvb (dead by then)

  dim3 b256(256);
  transpose_cvt<<<dim3(32, 32), b256, 0, stream>>>(Wq, WqkvT, 1024, 1024);
  transpose_cvt<<<dim3(32, 32), b256, 0, stream>>>(Wk, WqkvT + (size_t)1024 * 1024, 1024, 1024);
  transpose_cvt<<<dim3(32, 32), b256, 0, stream>>>(Wv, WqkvT + (size_t)2048 * 1024, 1024, 1024);
  transpose_cvt<<<dim3(32, 32), b256, 0, stream>>>(Wo, WoT, 1024, 1024);
  transpose_cvt<<<dim3(128, 32), b256, 0, stream>>>(W1, W1T, 1024, 4096);
  transpose_cvt<<<dim3(32, 128), b256, 0, stream>>>(W2, W2T, 4096, 1024);
  concat3<<<12, b256, 0, stream>>>(bq, bk, bv, bqkv);

  ln_kernel<<<4096, b256, 0, stream>>>(x, g1, be1, y1);
  gemm_bt<128, false, false, true, true><<<dim3(32, 24), b256, 0, stream>>>(y1, WqkvT, bqkv, nullptr, qkvb, 4096, 3072, 1024);
  prep_kv<<<dim3(64, 16), b256, 0, stream>>>(qkvb, Kp, Vp);
  attn_kernel<<<dim3(64, 16), b256, 0, stream>>>(qkvb, Kp, Vp, ctxb);
  gemm_bt<64, false, true, false, false><<<dim3(64, 8), b256, 0, stream>>>(ctxb, WoT, bo, x, x1, 4096, 1024, 1024);
  ln_kernel<<<4096, b256, 0, stream>>>(x1, g2, be2, y1);
  gemm_bt<128, true, false, true, false><<<dim3(32, 32), b256, 0, stream>>>(y1, W1T, b1, nullptr, hbuf, 4096, 4096, 1024);
  gemm_bt<64, false, true, false, false><<<dim3(64, 8), b256, 0, stream>>>(hbuf, W2T, b2, x1, out, 4096, 1024, 4096);
}

// Round 6
// 445.416 us; speedup vs baseline: 1.1160x; 1.1160x over previous
//
#include <hip/hip_runtime.h>
#include <cstdint>
#include <cstddef>

// S=4096, D=1024, H=16, DH=64, F=4096. fp32 in/out, bf16 MFMA compute.

typedef __attribute__((ext_vector_type(8))) __bf16 bf16x8;
typedef __attribute__((ext_vector_type(4))) float f32x4;
typedef __attribute__((ext_vector_type(2))) float f32x2;
typedef __attribute__((ext_vector_type(16))) float f32x16;
typedef __attribute__((ext_vector_type(4))) unsigned int u32x4;

__device__ inline unsigned short f2bf(float f) {
  unsigned int u = __float_as_uint(f);
  u += 0x7fffu + ((u >> 16) & 1u);   // round-to-nearest-even
  return (unsigned short)(u >> 16);
}

__device__ inline void gload_lds16(const unsigned short* g, unsigned short* l) {
  __builtin_amdgcn_global_load_lds(
      (const __attribute__((address_space(1))) void*)g,
      (__attribute__((address_space(3))) void*)l, 16, 0, 0);
}

// ---------------- transpose + fp32->bf16 : in[K][N] -> out[N][K] ----------------
__global__ __launch_bounds__(256) void transpose_cvt(const float* __restrict__ in,
                                                     unsigned short* __restrict__ out,
                                                     int K, int N) {
  __shared__ float t[32][33];
  int nb = blockIdx.x * 32, kb = blockIdx.y * 32;
  int tx = threadIdx.x & 31, ty = threadIdx.x >> 5;  // 32 x 8
#pragma unroll
  for (int i = 0; i < 32; i += 8)
    t[ty + i][tx] = in[(size_t)(kb + ty + i) * N + nb + tx];
  __syncthreads();
#pragma unroll
  for (int i = 0; i < 32; i += 8)
    out[(size_t)(nb + ty + i) * K + kb + tx] = f2bf(t[tx][ty + i]);
}

// ---------------- concat 3 bias vectors of 1024 ----------------
__global__ __launch_bounds__(256) void concat3(const float* __restrict__ a,
                                               const float* __restrict__ b,
                                               const float* __restrict__ c,
                                               float* __restrict__ out) {
  int i = blockIdx.x * 256 + threadIdx.x;  // 0..3071
  float v = (i < 1024) ? a[i] : (i < 2048 ? b[i - 1024] : c[i - 2048]);
  out[i] = v;
}

// ---------------- LayerNorm row (D=1024), output bf16 ----------------
__global__ __launch_bounds__(256) void ln_kernel(const float* __restrict__ x,
                                                 const float* __restrict__ gamma,
                                                 const float* __restrict__ beta,
                                                 unsigned short* __restrict__ y) {
  int row = blockIdx.x, tid = threadIdx.x;
  const float4 v = ((const float4*)(x + (size_t)row * 1024))[tid];
  float s = v.x + v.y + v.z + v.w;
#pragma unroll
  for (int off = 1; off < 64; off <<= 1) s += __shfl_xor(s, off);
  __shared__ float red1[4], red2[4];
  int wave = tid >> 6;
  if ((tid & 63) == 0) red1[wave] = s;
  __syncthreads();
  float mu = (red1[0] + red1[1] + red1[2] + red1[3]) * (1.0f / 1024.0f);
  float dx = v.x - mu, dy = v.y - mu, dz = v.z - mu, dw = v.w - mu;
  float s2 = dx * dx + dy * dy + dz * dz + dw * dw;
#pragma unroll
  for (int off = 1; off < 64; off <<= 1) s2 += __shfl_xor(s2, off);
  if ((tid & 63) == 0) red2[wave] = s2;
  __syncthreads();
  float var = (red2[0] + red2[1] + red2[2] + red2[3]) * (1.0f / 1024.0f);
  float inv = rsqrtf(var + 1e-6f);
  int c = tid * 4;
  ushort4 o;
  o.x = f2bf(dx * inv * gamma[c + 0] + beta[c + 0]);
  o.y = f2bf(dy * inv * gamma[c + 1] + beta[c + 1]);
  o.z = f2bf(dz * inv * gamma[c + 2] + beta[c + 2]);
  o.w = f2bf(dw * inv * gamma[c + 3] + beta[c + 3]);
  ((ushort4*)(y + (size_t)row * 1024))[tid] = o;
}

// ---------------- GEMM: C[M][N] = A[M][K](bf16) * BT[N][K](bf16) + bias ----------------
// m97 structure: TMx128 tile, BK=32, global_load_lds staging, pitch-32 LDS.
template <int TM, bool GELU, bool RES, bool OUTBF, bool SCALEQ>
__global__ __launch_bounds__(256) void gemm_bt(const unsigned short* __restrict__ A,
                                               const unsigned short* __restrict__ BT,
                                               const float* __restrict__ bias,
                                               const float* __restrict__ res,
                                               void* __restrict__ out,
                                               int M, int N, int K) {
  constexpr int AI = TM / 32;                 // acc i-tiles per wave (4 or 2)
  __shared__ unsigned short As[TM * 32];
  __shared__ unsigned short Bs[128 * 32];
  int bm = blockIdx.x, bn = blockIdx.y;
  int tid = threadIdx.x;
  int wave = tid >> 6, lane = tid & 63, quad = lane >> 4, l16 = lane & 15;
  int wrow = (wave >> 1) * (16 * AI), wcol = (wave & 1) * 64;
  f32x4 zero = {0.f, 0.f, 0.f, 0.f};
  f32x4 acc[AI][4];
#pragma unroll
  for (int i = 0; i < AI; i++)
#pragma unroll
    for (int j = 0; j < 4; j++) acc[i][j] = zero;

  const int srow = tid >> 2;            // 0..63
  const int scol = (tid & 3) * 8;       // shorts
  const unsigned short* aG0 = A + (size_t)(bm * TM + srow) * K + scol;
  const unsigned short* aG1 = A + (size_t)(bm * TM + 64 + srow) * K + scol;
  const unsigned short* bG0 = BT + (size_t)(bn * 128 + srow) * K + scol;
  const unsigned short* bG1 = BT + (size_t)(bn * 128 + 64 + srow) * K + scol;
  unsigned short* aL0 = As + (size_t)tid * 8;
  unsigned short* aL1 = As + (size_t)(256 + tid) * 8;
  unsigned short* bL0 = Bs + (size_t)tid * 8;
  unsigned short* bL1 = Bs + (size_t)(256 + tid) * 8;

  for (int k0 = 0; k0 < K; k0 += 32) {
    __syncthreads();
    gload_lds16(aG0 + k0, aL0);
    if (TM == 128) gload_lds16(aG1 + k0, aL1);
    gload_lds16(bG0 + k0, bL0);
    gload_lds16(bG1 + k0, bL1);
    __syncthreads();
    bf16x8 af[AI], bfr[4];
#pragma unroll
    for (int i = 0; i < AI; i++) af[i] = *(const bf16x8*)&As[(wrow + i * 16 + l16) * 32 + quad * 8];
#pragma unroll
    for (int j = 0; j < 4; j++) bfr[j] = *(const bf16x8*)&Bs[(wcol + j * 16 + l16) * 32 + quad * 8];
#pragma unroll
    for (int i = 0; i < AI; i++)
#pragma unroll
      for (int j = 0; j < 4; j++)
        acc[i][j] = __builtin_amdgcn_mfma_f32_16x16x32_bf16(af[i], bfr[j], acc[i][j], 0, 0, 0);
  }

#pragma unroll
  for (int i = 0; i < AI; i++) {
    int row = bm * TM + wrow + i * 16 + quad * 4;
#pragma unroll
    for (int j = 0; j < 4; j++) {
      int col = bn * 128 + wcol + j * 16 + l16;
      float bv = bias[col];
      // 0.125/sqrt(DH) * log2(e): softmax uses exp2
      float qs = (SCALEQ && col < 1024) ? 0.18033688f : 1.0f;
#pragma unroll
      for (int r = 0; r < 4; r++) {
        float v = (acc[i][j][r] + bv) * qs;
        if (GELU) v = 0.5f * v * (1.0f + erff(v * 0.70710678118654752440f));
        if (RES) v += res[(size_t)(row + r) * N + col];
        if (OUTBF)
          ((unsigned short*)out)[(size_t)(row + r) * N + col] = f2bf(v);
        else
          ((float*)out)[(size_t)(row + r) * N + col] = v;
      }
    }
  }
}

// ---------------- prep K/V tiles for attention (fragment-major) ----------------
// K: Kp[h][t][c][kv 64][8]  (c = d-chunk 0..7)  -> wave frag load = 2x512B contiguous
// V: Vp[h][t][c][d 64][8]   (c = kv-chunk 0..7) -> wave frag load = 2x512B contiguous
__global__ __launch_bounds__(256) void prep_kv(const unsigned short* __restrict__ qkv,
                                               unsigned short* __restrict__ Kp,
                                               unsigned short* __restrict__ Vp) {
  __shared__ unsigned short Vt[64 * 64];   // [d][kv]
  int t = blockIdx.x, h = blockIdx.y;
  int tid = threadIdx.x;
  const int r2 = tid >> 3, c0 = (tid & 7) * 8;
  size_t tb = ((size_t)h * 64 + t) * 4096;
  {
    const unsigned short* kp = qkv + (size_t)(t * 64 + r2) * 3072 + 1024 + h * 64 + c0;
    uint4 k0 = *(const uint4*)kp;
    uint4 k1 = *(const uint4*)(kp + (size_t)32 * 3072);
    int c = c0 >> 3;
    *(uint4*)(Kp + tb + c * 512 + r2 * 8) = k0;
    *(uint4*)(Kp + tb + c * 512 + (r2 + 32) * 8) = k1;
  }
  {
    const unsigned short* vp = qkv + (size_t)(t * 64 + 2 * r2) * 3072 + 2048 + h * 64 + c0;
    uint4 v0 = *(const uint4*)vp;          // kv=2*r2,   d=c0..c0+7
    uint4 v1 = *(const uint4*)(vp + 3072); // kv=2*r2+1
    const unsigned short* p0 = (const unsigned short*)&v0;
    const unsigned short* p1 = (const unsigned short*)&v1;
#pragma unroll
    for (int dd = 0; dd < 8; dd++) {
      unsigned int pk = (unsigned int)p0[dd] | ((unsigned int)p1[dd] << 16);
      *(unsigned int*)&Vt[(c0 + dd) * 64 + 2 * r2] = pk;
    }
  }
  __syncthreads();
#pragma unroll
  for (int u0 = 0; u0 < 2; u0++) {
    int u = tid + u0 * 256;           // 0..511 ; c = u>>6, d = u&63
    *(uint4*)(Vp + tb + u * 8) = *(const uint4*)&Vt[(u & 63) * 64 + (u >> 6) * 8];
  }
}

// ---------------- Flash attention: fragment-major K/V -> ctx[S][1024] bf16 ----------------
// grid = (S/64, H), block 256 (4 waves): wave = (qsub, kvh). Q + P in registers.
// NO LDS / NO barriers in the K-loop: every MFMA fragment is a coalesced global load
// from the prepped layouts (L2/L3-resident). Cross-lane P assembly via v_permlane32_swap.
// No-max base-2 softmax (0.125*log2e folded into Q by QKV epilogue).
__global__ __launch_bounds__(256, 3) void attn_kernel(const unsigned short* __restrict__ qkv,
                                                      const unsigned short* __restrict__ Kp,
                                                      const unsigned short* __restrict__ Vp,
                                                      unsigned short* __restrict__ ctx) {
  __shared__ float comb[2 * 32 * 64];   // kvh=1 partial O (16 KB)
  __shared__ float lpart[4 * 32];       // [kvh][qsub][q]
  int qt = blockIdx.x, h = blockIdx.y;
  int tid = threadIdx.x;
  int w = tid >> 6, lane = tid & 63;
  int l31 = lane & 31, hi = lane >> 5;
  int qsub = w & 1, kvh = w >> 1;

  // Q fragments (B-operand: n=q=l31, k=d). Pre-scaled by 0.125*log2e in QKV epilogue.
  bf16x8 qf[4];
  {
    const unsigned short* qp = qkv + (size_t)(qt * 64 + qsub * 32 + l31) * 3072 + h * 64 + hi * 8;
#pragma unroll
    for (int kk = 0; kk < 4; kk++) qf[kk] = *(const bf16x8*)(qp + kk * 16);
  }

  const size_t hb = (size_t)h * 64 * 4096;
  // K frag (kk): Kp + hb + t*4096 + (kk*2+hi)*512 + (kvh*32+l31)*8
  const unsigned short* kB = Kp + hb + hi * 512 + (kvh * 32 + l31) * 8;
  // V frag A (kk): Vp + hb + t*4096 + (kvh*4+kk*2+hi)*512 + l31*8 ; frag B: +256
  const unsigned short* vB = Vp + hb + (kvh * 4 + hi) * 512 + l31 * 8;

  f32x16 accO0, accO1;
  f32x2 lp2 = {0.f, 0.f};
#pragma unroll
  for (int r = 0; r < 16; r++) { accO0[r] = 0.f; accO1[r] = 0.f; }

  bf16x8 kf[4];
#pragma unroll
  for (int kk = 0; kk < 4; kk++) kf[kk] = *(const bf16x8*)(kB + kk * 1024);

  for (int t = 0; t < 64; t++) {
    // issue V(t) early: consumed after QK + softmax (~200 cyc later)
    const unsigned short* vt = vB + (size_t)t * 4096;
    bf16x8 vA0 = *(const bf16x8*)(vt);
    bf16x8 vA1 = *(const bf16x8*)(vt + 1024);
    bf16x8 vB0 = *(const bf16x8*)(vt + 256);
    bf16x8 vB1 = *(const bf16x8*)(vt + 1024 + 256);

    // S^T tile [32 kv][32 q]: A = K (m=kv), B = Q^T (n=q)
    f32x16 accS;
#pragma unroll
    for (int r = 0; r < 16; r++) accS[r] = 0.f;
#pragma unroll
    for (int kk = 0; kk < 4; kk++)
      accS = __builtin_amdgcn_mfma_f32_32x32x16_bf16(kf[kk], qf[kk], accS, 0, 0, 0);

    // issue K(t+1): consumed after softmax + PV (~200 cyc later)
    if (t < 63) {
      const unsigned short* kt = kB + (size_t)(t + 1) * 4096;
#pragma unroll
      for (int kk = 0; kk < 4; kk++) kf[kk] = *(const bf16x8*)(kt + kk * 1024);
    }

    // P = 2^S; packed row-sum; truncation-pack pairs to bf16
    unsigned int pd[8];
#pragma unroll
    for (int i = 0; i < 8; i++) {
      float a = __builtin_amdgcn_exp2f(accS[2 * i]);
      float b = __builtin_amdgcn_exp2f(accS[2 * i + 1]);
      f32x2 ab = {a, b};
      lp2 += ab;
      pd[i] = __builtin_amdgcn_perm(__float_as_uint(b), __float_as_uint(a), 0x07060302);
    }
    // assemble P A-fragments: one v_permlane32_swap per dword pair
    asm("v_permlane32_swap_b32 %0, %1" : "+v"(pd[0]), "+v"(pd[2]));
    asm("v_permlane32_swap_b32 %0, %1" : "+v"(pd[1]), "+v"(pd[3]));
    asm("v_permlane32_swap_b32 %0, %1" : "+v"(pd[4]), "+v"(pd[6]));
    asm("v_permlane32_swap_b32 %0, %1" : "+v"(pd[5]), "+v"(pd[7]));
    u32x4 f0 = {pd[0], pd[1], pd[2], pd[3]};
    u32x4 f1 = {pd[4], pd[5], pd[6], pd[7]};
    bf16x8 pa0 = __builtin_bit_cast(bf16x8, f0);
    bf16x8 pa1 = __builtin_bit_cast(bf16x8, f1);

    // O += P V
    accO0 = __builtin_amdgcn_mfma_f32_32x32x16_bf16(pa0, vA0, accO0, 0, 0, 0);
    accO1 = __builtin_amdgcn_mfma_f32_32x32x16_bf16(pa0, vB0, accO1, 0, 0, 0);
    accO0 = __builtin_amdgcn_mfma_f32_32x32x16_bf16(pa1, vA1, accO0, 0, 0, 0);
    accO1 = __builtin_amdgcn_mfma_f32_32x32x16_bf16(pa1, vB1, accO1, 0, 0, 0);
  }

  // ---- cross-wave combine (kv halves) ----
  float lp = lp2.x + lp2.y;
  lp += __shfl_xor(lp, 32);
  if (hi == 0) lpart[(kvh * 2 + qsub) * 32 + l31] = lp;
  if (kvh == 1) {
#pragma unroll
    for (int r = 0; r < 16; r++) {
      int q = (r & 3) + 8 * (r >> 2) + 4 * hi;
      comb[(qsub * 32 + q) * 64 + l31] = accO0[r];
      comb[(qsub * 32 + q) * 64 + 32 + l31] = accO1[r];
    }
  }
  __syncthreads();
  if (kvh == 0) {
#pragma unroll
    for (int r = 0; r < 16; r++) {
      int q = (r & 3) + 8 * (r >> 2) + 4 * hi;
      float l = lpart[qsub * 32 + q] + lpart[(2 + qsub) * 32 + q];
      float inv = 1.0f / l;
      float v0 = (accO0[r] + comb[(qsub * 32 + q) * 64 + l31]) * inv;
      float v1 = (accO1[r] + comb[(qsub * 32 + q) * 64 + 32 + l31]) * inv;
      int row = qt * 64 + qsub * 32 + q;
      size_t o = (size_t)row * 1024 + h * 64;
      ctx[o + l31] = f2bf(v0);
      ctx[o + 32 + l31] = f2bf(v1);
    }
  }
}

// ---------------- launcher ----------------
extern "C" void kernel_launch(void* const* d_in, const int* in_sizes, int n_in,
                              void* d_out, int out_size, void* d_ws, size_t ws_size,
                              hipStream_t stream) {
  const float* x   = (const float*)d_in[0];
  const float* Wq  = (const float*)d_in[1];
  const float* bq  = (const float*)d_in[2];
  const float* Wk  = (const float*)d_in[3];
  const float* bk  = (const float*)d_in[4];
  const float* Wv  = (const float*)d_in[5];
  const float* bv  = (const float*)d_in[6];
  const float* Wo  = (const float*)d_in[7];
  const float* bo  = (const float*)d_in[8];
  const float* g1  = (const float*)d_in[9];
  const float* be1 = (const float*)d_in[10];
  const float* g2  = (const float*)d_in[11];
  const float* be2 = (const float*)d_in[12];
  const float* W1  = (const float*)d_in[13];
  const float* b1  = (const float*)d_in[14];
  const float* W2  = (const float*)d_in[15];
  const float* b2  = (const float*)d_in[16];
  float* out = (float*)d_out;

  char* p = (char*)d_ws;
  unsigned short* WqkvT = (unsigned short*)p; p += (size_t)3072 * 1024 * 2;  // [3072][1024]
  unsigned short* WoT   = (unsigned short*)p; p += (size_t)1024 * 1024 * 2;  // [1024][1024]
  unsigned short* W1T   = (unsigned short*)p; p += (size_t)4096 * 1024 * 2;  // [4096][1024]
  unsigned short* W2T   = (unsigned short*)p; p += (size_t)1024 * 4096 * 2;  // [1024][4096]
  float*          bqkv  = (float*)p;          p += 16384;                    // [3072]
  unsigned short* y1    = (unsigned short*)p; p += (size_t)4096 * 1024 * 2;  // LN out
  unsigned short* qkvb  = (unsigned short*)p; p += (size_t)4096 * 3072 * 2;  // [S][3072]
  unsigned short* ctxb  = (unsigned short*)p; p += (size_t)4096 * 1024 * 2;  // [S][1024]
  float*          x1    = (float*)p;          p += (size_t)4096 * 1024 * 4;  // residual fp32
  unsigned short* Kp    = (unsigned short*)p; p += (size_t)16 * 64 * 4096 * 2;  // prepped K tiles
  unsigned short* Vp    = (unsigned short*)p; p += (size_t)16 * 64 * 4096 * 2;  // prepped V tiles
  unsigned short* hbuf  = qkvb;  // [S][4096] bf16 aliases qkvb (dead by then)

  dim3 b256(256);
  transpose_cvt<<<dim3(32, 32), b256, 0, stream>>>(Wq, WqkvT, 1024, 1024);
  transpose_cvt<<<dim3(32, 32), b256, 0, stream>>>(Wk, WqkvT + (size_t)1024 * 1024, 1024, 1024);
  transpose_cvt<<<dim3(32, 32), b256, 0, stream>>>(Wv, WqkvT + (size_t)2048 * 1024, 1024, 1024);
  transpose_cvt<<<dim3(32, 32), b256, 0, stream>>>(Wo, WoT, 1024, 1024);
  transpose_cvt<<<dim3(128, 32), b256, 0, stream>>>(W1, W1T, 1024, 4096);
  transpose_cvt<<<dim3(32, 128), b256, 0, stream>>>(W2, W2T, 4096, 1024);
  concat3<<<12, b256, 0, stream>>>(bq, bk, bv, bqkv);

  ln_kernel<<<4096, b256, 0, stream>>>(x, g1, be1, y1);
  gemm_bt<128, false, false, true, true><<<dim3(32, 24), b256, 0, stream>>>(y1, WqkvT, bqkv, nullptr, qkvb, 4096, 3072, 1024);
  prep_kv<<<dim3(64, 16), b256, 0, stream>>>(qkvb, Kp, Vp);
  attn_kernel<<<dim3(64, 16), b256, 0, stream>>>(qkvb, Kp, Vp, ctxb);
  gemm_bt<64, false, true, false, false><<<dim3(64, 8), b256, 0, stream>>>(ctxb, WoT, bo, x, x1, 4096, 1024, 1024);
  ln_kernel<<<4096, b256, 0, stream>>>(x1, g2, be2, y1);
  gemm_bt<128, true, false, true, false><<<dim3(32, 32), b256, 0, stream>>>(y1, W1T, b1, nullptr, hbuf, 4096, 4096, 1024);
  gemm_bt<64, false, true, false, false><<<dim3(64, 8), b256, 0, stream>>>(hbuf, W2T, b2, x1, out, 4096, 1024, 4096);
}